// Round 10
// baseline (12705.798 us; speedup 1.0000x reference)
//
#include <hip/hip_runtime.h>
#include <hip/hip_bf16.h>
#include <hip/hip_fp16.h>
#include <stdint.h>

#define BB  256
#define TT  512
#define FF  8
#define HH  256
#define H4  1024
#define DEC 35
#define NWG 16
#define MW  16

typedef __attribute__((ext_vector_type(8))) short short8v;
typedef __attribute__((ext_vector_type(4))) float f32x4;

// dynamic-LDS layout (bytes)
#define OFF_SLICE 0             // 8 waves * 2 bufs * 8KB slice = 131072
#define OFF_HHI  131072         // h hi A-frags (single buffer): 8192
#define OFF_HLO  139264         // h lo A-frags: 8192
#define OFF_MLP  147456         // sWmlp 512 f32 = 2048
#define OFF_SM   149504         // 6 f32 + pad = 32
#define SMEM_TOT 149536

__device__ __forceinline__ unsigned short f2bf(float x) {
    unsigned u = __float_as_uint(x);
    u += 0x7fffu + ((u >> 16) & 1u);          // RNE
    return (unsigned short)(u >> 16);
}
__device__ __forceinline__ float bf2f(unsigned s) { return __uint_as_float(s << 16); }
__device__ __forceinline__ float2 h2tof2(unsigned u) {
    __half2 h2 = *reinterpret_cast<const __half2*>(&u);
    return __half22float2(h2);
}
__device__ __forceinline__ float sigf(float x) {
    x = fminf(fmaxf(x, -30.f), 30.f);
    return 1.0f / (1.0f + __expf(-x));
}
__device__ __forceinline__ float tanh_(float x) {
    x = fminf(fmaxf(x, -15.f), 15.f);
    float e = __expf(2.0f * x);
    return (e - 1.0f) / (e + 1.0f);
}

// ===================== prep kernels (unchanged, proven) =====================

__global__ void prep_consts(const float* __restrict__ W_pe, const float* __restrict__ b_pe,
                            const float* __restrict__ embed, const float* __restrict__ W_x,
                            const float* __restrict__ b_lstm,
                            const float* __restrict__ bn_gamma, const float* __restrict__ bn_beta,
                            const float* __restrict__ bn_mean, const float* __restrict__ bn_var,
                            __half* __restrict__ wpxh, float* __restrict__ zbias,
                            float* __restrict__ zdec0) {
    int n = blockIdx.x * 256 + threadIdx.x;
    float acc[FF];
    #pragma unroll
    for (int f = 0; f < FF; ++f) acc[f] = 0.f;
    float bsum = 0.f, dsum = 0.f;
    for (int m = 0; m < HH; ++m) {
        float wx = W_x[m * H4 + n];
        #pragma unroll
        for (int f = 0; f < FF; ++f) acc[f] = fmaf(W_pe[f * HH + m], wx, acc[f]);
        bsum = fmaf(b_pe[m], wx, bsum);
        dsum = fmaf(embed[m], wx, dsum);
    }
    float zb = b_lstm[n] + bsum;
    #pragma unroll
    for (int f = 0; f < FF; ++f) {
        float s  = bn_gamma[f] * rsqrtf(bn_var[f] + 1e-3f);
        float sh = bn_beta[f] - bn_mean[f] * s;
        wpxh[n * FF + f] = __float2half(s * acc[f]);
        zb = fmaf(sh, acc[f], zb);
    }
    zbias[n] = zb;
    zdec0[n] = b_lstm[n] + dsum;
}

// B-frags: frag[(nt*8+kc)*64+ln][j] = W[k = kc*32 + 8*(ln>>4) + j][nt*16 + (ln&15)]
__global__ void prep_wfrag(const float* __restrict__ W_x, const float* __restrict__ W_h,
                           short8v* __restrict__ whf, short8v* __restrict__ wsf) {
    int nt = blockIdx.x >> 3, kc = blockIdx.x & 7, ln = threadIdx.x;
    int n = nt * 16 + (ln & 15), q = ln >> 4;
    short8v vh, vs;
    #pragma unroll
    for (int j = 0; j < 8; ++j) {
        int k = kc * 32 + q * 8 + j;
        float wh = W_h[k * H4 + n], wx = W_x[k * H4 + n];
        vh[j] = (short)f2bf(wh);
        vs[j] = (short)f2bf(wx + wh);
    }
    whf[blockIdx.x * 64 + ln] = vh;
    wsf[blockIdx.x * 64 + ln] = vs;
}

// ===================== main recurrent kernel =====================
// 16 WGs x 512 thr (8 waves). Wave w owns tiles ntv[tl]=(tl>>1)*16+2w+(tl&1)
// (all 4 gates of units [32w,32w+32)) -- round-7 structure, numerics proven.
// KEY CHANGE vs rounds 5-9: weights NEVER touch VGPRs. All 64 tiles stream
// global->LDS via __builtin_amdgcn_global_load_lds into wave-private
// double-buffered 8KB kc-slice buffers, with counted s_waitcnt vmcnt(8)
// (prefetch slice kc+1 while computing kc; drain to 0 only at kc=7).
// Rounds 5-9 evidence: arch-VGPR budget is 128 @512thr and short8v weight
// dbufs (4 VGPR each) alone blew it -> 9-18MB/dispatch scratch spills.
// This kernel's arch live set ~90 (wpx 32 + ah/al 8 + transient ds results).
__global__ __launch_bounds__(512) void lstm_rec8(
    const short8v* __restrict__ whf, const short8v* __restrict__ wsf,
    const uint4* __restrict__ wpx4,
    const float* __restrict__ pulse,
    const float* __restrict__ zbias, const float* __restrict__ zdec0,
    const float* __restrict__ blstm,
    const float* __restrict__ W_mlp, const float* __restrict__ b_mlp,
    const float* __restrict__ scale_w, const float* __restrict__ scale_b,
    float* __restrict__ out) {
    extern __shared__ char smem[];
    short8v* ldsHI = (short8v*)(smem + OFF_HHI);
    short8v* ldsLO = (short8v*)(smem + OFF_HLO);
    unsigned short* hHIs = (unsigned short*)(smem + OFF_HHI);
    unsigned short* hLOs = (unsigned short*)(smem + OFF_HLO);
    float*   sWmlp = (float*)(smem + OFF_MLP);
    float*   sm    = (float*)(smem + OFF_SM);

    const int tid = threadIdx.x, g = blockIdx.x;
    const int w = tid >> 6, ln = tid & 63;
    const int col = ln & 15, q = ln >> 4;
    const int sliceBase = OFF_SLICE + w * 16384;   // 2 x 8KB per wave

    int ntv[8];
    #pragma unroll
    for (int tl = 0; tl < 8; ++tl) ntv[tl] = (tl >> 1) * 16 + 2 * w + (tl & 1);

    // ---- init ----
    {
        short8v zz = {};
        ldsHI[tid] = zz;          // 512 entries each, 512 threads
        ldsLO[tid] = zz;
    }
    for (int i = tid; i < HH * 2; i += 512) sWmlp[i] = W_mlp[i];
    if (tid < 2) { sm[tid] = b_mlp[tid]; sm[2 + tid] = scale_w[tid]; sm[4 + tid] = scale_b[tid]; }

    uint4 wpx[8];
    float zb[8];
    #pragma unroll
    for (int tl = 0; tl < 8; ++tl) {
        int n = ntv[tl] * 16 + col;
        wpx[tl] = wpx4[n];
        zb[tl]  = zbias[n];
    }

    float c[8];
    #pragma unroll
    for (int i = 0; i < 8; ++i) c[i] = 0.f;

    const float* pbase = pulse + (size_t)(g * MW) * TT * FF;
    __syncthreads();

    // issue one kc-slice (8 tiles x 1KB) of SRC into this wave's slice buffer.
    // LDS dest is wave-uniform base + lane*16 (HW semantics); global src per-lane.
#define ISSUE_SLICE(SRC, kcv) do {                                              \
        _Pragma("unroll")                                                       \
        for (int tl_ = 0; tl_ < 8; ++tl_) {                                     \
            const short8v* gsrc_ = (SRC) + (size_t)(ntv[tl_] * 8 + (kcv)) * 64 + ln; \
            __builtin_amdgcn_global_load_lds(                                   \
                (const __attribute__((address_space(1))) void*)gsrc_,           \
                (__attribute__((address_space(3))) void*)(smem + sliceBase + ((kcv) & 1) * 8192 + tl_ * 1024), \
                16, 0, 0);                                                      \
        }                                                                       \
    } while (0)

    // full K-chain for 8 tiles from SRC via slice double-buffer
#define CHAIN(SRC) do {                                                         \
        ISSUE_SLICE(SRC, 0);                                                    \
        _Pragma("unroll")                                                       \
        for (int kc = 0; kc < 8; ++kc) {                                        \
            if (kc < 7) {                                                       \
                ISSUE_SLICE(SRC, kc + 1);                                       \
                asm volatile("s_waitcnt vmcnt(8)" ::: "memory");                \
            } else {                                                            \
                asm volatile("s_waitcnt vmcnt(0)" ::: "memory");                \
            }                                                                   \
            __builtin_amdgcn_sched_barrier(0);                                  \
            short8v ah = ldsHI[kc * 64 + ln];                                   \
            short8v al = ldsLO[kc * 64 + ln];                                   \
            const short8v* sl_ = (const short8v*)(smem + sliceBase + (kc & 1) * 8192); \
            _Pragma("unroll")                                                   \
            for (int tl_ = 0; tl_ < 8; ++tl_) {                                 \
                short8v b_ = sl_[tl_ * 64 + ln];                                \
                acc[tl_] = __builtin_amdgcn_mfma_f32_16x16x32_bf16(ah, b_, acc[tl_], 0, 0, 0); \
                acc[tl_] = __builtin_amdgcn_mfma_f32_16x16x32_bf16(al, b_, acc[tl_], 0, 0, 0); \
            }                                                                   \
        }                                                                       \
    } while (0)

#define GATES_WRITE() do {                                                      \
        _Pragma("unroll")                                                       \
        for (int p = 0; p < 2; ++p)                                             \
            _Pragma("unroll")                                                   \
            for (int r = 0; r < 4; ++r) {                                       \
                float cc = sigf(acc[2 + p][r]) * c[p * 4 + r] + sigf(acc[p][r]) * tanh_(acc[4 + p][r]); \
                c[p * 4 + r] = cc;                                              \
                float hh = sigf(acc[6 + p][r]) * tanh_(cc);                     \
                unsigned short hi = f2bf(hh);                                   \
                float lo = hh - bf2f(hi);                                       \
                int ad = w * 512 + (2 * p + (col >> 3)) * 128 + (4 * q + r) * 8 + (col & 7); \
                hHIs[ad] = hi;                                                  \
                hLOs[ad] = f2bf(lo);                                            \
            }                                                                   \
    } while (0)

    // ---- encoder: 512 steps ----
    for (int t = 0; t < TT; ++t) {
        float4 xc[4][2];
        #pragma unroll
        for (int r = 0; r < 4; ++r) {
            const float* pr = pbase + (size_t)(4 * q + r) * TT * FF + (size_t)t * FF;
            xc[r][0] = ((const float4*)pr)[0];
            xc[r][1] = ((const float4*)pr)[1];
        }
        f32x4 acc[8];
        #pragma unroll
        for (int tl = 0; tl < 8; ++tl) {
            float wv[8];
            float2 d;
            d = h2tof2(wpx[tl].x); wv[0] = d.x; wv[1] = d.y;
            d = h2tof2(wpx[tl].y); wv[2] = d.x; wv[3] = d.y;
            d = h2tof2(wpx[tl].z); wv[4] = d.x; wv[5] = d.y;
            d = h2tof2(wpx[tl].w); wv[6] = d.x; wv[7] = d.y;
            f32x4 av;
            #pragma unroll
            for (int r = 0; r < 4; ++r) {
                float s = zb[tl];
                s = fmaf(xc[r][0].x, wv[0], s); s = fmaf(xc[r][0].y, wv[1], s);
                s = fmaf(xc[r][0].z, wv[2], s); s = fmaf(xc[r][0].w, wv[3], s);
                s = fmaf(xc[r][1].x, wv[4], s); s = fmaf(xc[r][1].y, wv[5], s);
                s = fmaf(xc[r][1].z, wv[6], s); s = fmaf(xc[r][1].w, wv[7], s);
                av[r] = s;
            }
            acc[tl] = av;
        }
        CHAIN(whf);
        __syncthreads();      // all h-frag reads complete
        GATES_WRITE();
        __syncthreads();      // new h visible
    }

    // ---- decoder: 35 steps ----
    float zd0[8], bl[8];
    #pragma unroll
    for (int tl = 0; tl < 8; ++tl) {
        zd0[tl] = zdec0[ntv[tl] * 16 + col];
        bl[tl]  = blstm[ntv[tl] * 16 + col];
    }

    for (int s = 0; s < DEC; ++s) {
        f32x4 acc[8];
        if (s == 0) {
            #pragma unroll
            for (int tl = 0; tl < 8; ++tl) {
                f32x4 av; av[0] = zd0[tl]; av[1] = zd0[tl]; av[2] = zd0[tl]; av[3] = zd0[tl];
                acc[tl] = av;
            }
            CHAIN(whf);
        } else {
            #pragma unroll
            for (int tl = 0; tl < 8; ++tl) {
                f32x4 av; av[0] = bl[tl]; av[1] = bl[tl]; av[2] = bl[tl]; av[3] = bl[tl];
                acc[tl] = av;
            }
            CHAIN(wsf);
        }
        __syncthreads();
        GATES_WRITE();
        __syncthreads();

        // MLP head from split-h frags (round-8-proven addressing)
        {
            int m = tid >> 5, j = (tid >> 4) & 1, uc = tid & 15;
            float p2 = 0.f;
            #pragma unroll
            for (int i = 0; i < 16; ++i) {
                int u = i * 16 + uc;
                int ad = (u >> 5) * 512 + ((u >> 3) & 3) * 128 + m * 8 + (u & 7);
                float hv = bf2f(hHIs[ad]) + bf2f(hLOs[ad]);
                p2 = fmaf(hv, sWmlp[u * 2 + j], p2);
            }
            p2 += __shfl_down(p2, 8, 16);
            p2 += __shfl_down(p2, 4, 16);
            p2 += __shfl_down(p2, 2, 16);
            p2 += __shfl_down(p2, 1, 16);
            if (uc == 0) {
                float pr = p2 + sm[j];
                out[((size_t)(g * MW + m) * DEC + s) * 2 + j] = pr * sm[2 + j] + sm[4 + j];
            }
        }
        // next iteration's post-chain barrier orders these reads vs next write
    }
#undef ISSUE_SLICE
#undef CHAIN
#undef GATES_WRITE
}

// ===================== fallback (round-2, proven) =====================
__global__ void prep_weights(const float* __restrict__ Wx, const float* __restrict__ Wh,
                             __hip_bfloat16* __restrict__ wxb,
                             __hip_bfloat16* __restrict__ whb,
                             __hip_bfloat16* __restrict__ wsb) {
    int i = blockIdx.x * 256 + threadIdx.x;
    if (i < HH * H4) {
        float x = Wx[i], h = Wh[i];
        wxb[i] = __float2bfloat16(x);
        whb[i] = __float2bfloat16(h);
        wsb[i] = __float2bfloat16(x + h);
    }
}

template<bool BF16W>
__device__ __forceinline__ void matvec2(const void* __restrict__ W,
                                        const float* __restrict__ vec,
                                        int tid, float& z0, float& z1) {
    if constexpr (BF16W) {
        const uint32_t* Wp = (const uint32_t*)W;
        #pragma unroll 8
        for (int k = 0; k < HH; ++k) {
            uint32_t w = Wp[(size_t)k * (H4 / 2) + tid];
            float s = vec[k];
            union { uint32_t u; float f; } lo, hi;
            lo.u = w << 16;
            hi.u = w & 0xffff0000u;
            z0 = fmaf(s, lo.f, z0);
            z1 = fmaf(s, hi.f, z1);
        }
    } else {
        const float2* Wp = (const float2*)W;
        #pragma unroll 8
        for (int k = 0; k < HH; ++k) {
            float2 w = Wp[(size_t)k * (H4 / 2) + tid];
            float s = vec[k];
            z0 = fmaf(s, w.x, z0);
            z1 = fmaf(s, w.y, z1);
        }
    }
}

__device__ __forceinline__ float sigmoidf_(float x) { return 1.0f / (1.0f + expf(-x)); }

template<bool BF16W>
__global__ __launch_bounds__(512)
void lstm_persist(const float* __restrict__ pulse,
                  const float* __restrict__ bn_gamma, const float* __restrict__ bn_beta,
                  const float* __restrict__ bn_mean, const float* __restrict__ bn_var,
                  const float* __restrict__ W_pe, const float* __restrict__ b_pe,
                  const float* __restrict__ embed,
                  const float* __restrict__ W_x, const float* __restrict__ W_h,
                  const float* __restrict__ b_lstm,
                  const float* __restrict__ W_mlp, const float* __restrict__ b_mlp,
                  const float* __restrict__ scale_w, const float* __restrict__ scale_b,
                  const void* __restrict__ WxQ, const void* __restrict__ WhQ,
                  const void* __restrict__ WsQ,
                  float* __restrict__ out) {
    __shared__ float sWpe2[FF * HH];
    __shared__ float sbpe2[HH];
    __shared__ float sbl[H4];
    __shared__ float sWmlp[HH * 2];
    __shared__ float sbuf[HH];
    __shared__ float hbuf[HH];
    __shared__ float cbuf[HH];
    __shared__ float zbuf[H4];
    __shared__ float bnsc[FF], bnsh[FF];
    __shared__ float smisc[6];

    const int tid = threadIdx.x;
    const int bb  = blockIdx.x;

    if (tid < FF) {
        float s = bn_gamma[tid] * rsqrtf(bn_var[tid] + 1e-3f);
        bnsc[tid] = s;
        bnsh[tid] = bn_beta[tid] - bn_mean[tid] * s;
    }
    if (tid < 2) {
        smisc[tid]     = b_mlp[tid];
        smisc[2 + tid] = scale_w[tid];
        smisc[4 + tid] = scale_b[tid];
    }
    for (int i = tid; i < H4; i += 512) sbl[i] = b_lstm[i];
    for (int i = tid; i < 2 * HH; i += 512) sWmlp[i] = W_mlp[i];
    for (int i = tid; i < HH; i += 512) { hbuf[i] = 0.f; cbuf[i] = 0.f; }
    __syncthreads();
    for (int i = tid; i < FF * HH; i += 512) sWpe2[i] = W_pe[i] * bnsc[i / HH];
    for (int i = tid; i < HH; i += 512) {
        float a = b_pe[i];
        #pragma unroll
        for (int f = 0; f < FF; ++f) a = fmaf(bnsh[f], W_pe[f * HH + i], a);
        sbpe2[i] = a;
    }
    __syncthreads();
    if (tid >= HH && tid < 2 * HH) {
        int u = tid - HH;
        const float* pr = pulse + (size_t)bb * TT * FF;
        float acc = sbpe2[u];
        #pragma unroll
        for (int f = 0; f < FF; ++f) acc = fmaf(pr[f], sWpe2[f * HH + u], acc);
        sbuf[u] = acc;
    }
    __syncthreads();

    for (int t = 0; t < TT; ++t) {
        float z0 = sbl[2 * tid], z1 = sbl[2 * tid + 1];
        if constexpr (BF16W) {
            matvec2<true>(WxQ, sbuf, tid, z0, z1);
            matvec2<true>(WhQ, hbuf, tid, z0, z1);
        } else {
            matvec2<false>(W_x, sbuf, tid, z0, z1);
            matvec2<false>(W_h, hbuf, tid, z0, z1);
        }
        zbuf[2 * tid] = z0; zbuf[2 * tid + 1] = z1;
        __syncthreads();
        if (tid < HH) {
            float iv = zbuf[tid], fv = zbuf[tid + HH];
            float gv = zbuf[tid + 2 * HH], ov = zbuf[tid + 3 * HH];
            float c = sigmoidf_(fv) * cbuf[tid] + sigmoidf_(iv) * tanhf(gv);
            cbuf[tid] = c;
            hbuf[tid] = sigmoidf_(ov) * tanhf(c);
        } else if (tid < 2 * HH) {
            int u = tid - HH;
            float acc;
            if (t + 1 < TT) {
                const float* pr = pulse + ((size_t)bb * TT + (t + 1)) * FF;
                acc = sbpe2[u];
                #pragma unroll
                for (int f = 0; f < FF; ++f) acc = fmaf(pr[f], sWpe2[f * HH + u], acc);
            } else {
                acc = embed[u];
            }
            sbuf[u] = acc;
        }
        __syncthreads();
    }

    for (int s = 0; s < DEC; ++s) {
        float z0 = sbl[2 * tid], z1 = sbl[2 * tid + 1];
        if (s == 0) {
            if constexpr (BF16W) {
                matvec2<true>(WxQ, sbuf, tid, z0, z1);
                matvec2<true>(WhQ, hbuf, tid, z0, z1);
            } else {
                matvec2<false>(W_x, sbuf, tid, z0, z1);
                matvec2<false>(W_h, hbuf, tid, z0, z1);
            }
        } else {
            if constexpr (BF16W) {
                matvec2<true>(WsQ, hbuf, tid, z0, z1);
            } else {
                matvec2<false>(W_x, hbuf, tid, z0, z1);
                matvec2<false>(W_h, hbuf, tid, z0, z1);
            }
        }
        zbuf[2 * tid] = z0; zbuf[2 * tid + 1] = z1;
        __syncthreads();
        if (tid < HH) {
            float iv = zbuf[tid], fv = zbuf[tid + HH];
            float gv = zbuf[tid + 2 * HH], ov = zbuf[tid + 3 * HH];
            float c = sigmoidf_(fv) * cbuf[tid] + sigmoidf_(iv) * tanhf(gv);
            cbuf[tid] = c;
            hbuf[tid] = sigmoidf_(ov) * tanhf(c);
        }
        __syncthreads();
        if (tid < 128) {
            int j = tid >> 6, lane = tid & 63;
            float p = 0.f;
            #pragma unroll
            for (int u = lane; u < HH; u += 64) p = fmaf(hbuf[u], sWmlp[u * 2 + j], p);
            p += __shfl_down(p, 32); p += __shfl_down(p, 16); p += __shfl_down(p, 8);
            p += __shfl_down(p, 4);  p += __shfl_down(p, 2);  p += __shfl_down(p, 1);
            if (lane == 0) {
                float pr2 = p + smisc[j];
                out[((size_t)bb * DEC + s) * 2 + j] = pr2 * smisc[2 + j] + smisc[4 + j];
            }
        }
        __syncthreads();
    }
}

extern "C" void kernel_launch(void* const* d_in, const int* in_sizes, int n_in,
                              void* d_out, int out_size, void* d_ws, size_t ws_size,
                              hipStream_t stream) {
    const float* pulse    = (const float*)d_in[0];
    const float* bn_gamma = (const float*)d_in[1];
    const float* bn_beta  = (const float*)d_in[2];
    const float* bn_mean  = (const float*)d_in[3];
    const float* bn_var   = (const float*)d_in[4];
    const float* W_pe     = (const float*)d_in[5];
    const float* b_pe     = (const float*)d_in[6];
    const float* embed    = (const float*)d_in[7];
    const float* W_x      = (const float*)d_in[8];
    const float* W_h      = (const float*)d_in[9];
    const float* b_lstm   = (const float*)d_in[10];
    const float* W_mlp    = (const float*)d_in[11];
    const float* b_mlp    = (const float*)d_in[12];
    const float* scale_w  = (const float*)d_in[13];
    const float* scale_b  = (const float*)d_in[14];
    float* out = (float*)d_out;

    // ws layout: whf 512K | wsf 512K | wpxh 16K | zbias 4K | zdec0 4K
    const size_t SZ_WF  = (size_t)64 * 8 * 64 * 16;     // 524288
    const size_t SZ_PXH = (size_t)H4 * FF * 2;          // 16384
    const size_t needA = 2 * SZ_WF + SZ_PXH + 2 * (size_t)H4 * 4;

    if (ws_size >= needA) {
        short8v* whf   = (short8v*)d_ws;
        short8v* wsf   = (short8v*)((char*)d_ws + SZ_WF);
        __half*  wpxh  = (__half*)((char*)d_ws + 2 * SZ_WF);
        float*   zbias = (float*)((char*)d_ws + 2 * SZ_WF + SZ_PXH);
        float*   zdec0 = zbias + H4;

        hipFuncSetAttribute((const void*)lstm_rec8,
                            hipFuncAttributeMaxDynamicSharedMemorySize, SMEM_TOT);

        prep_consts<<<4, 256, 0, stream>>>(W_pe, b_pe, embed, W_x, b_lstm,
                                           bn_gamma, bn_beta, bn_mean, bn_var,
                                           wpxh, zbias, zdec0);
        prep_wfrag<<<512, 64, 0, stream>>>(W_x, W_h, whf, wsf);
        lstm_rec8<<<NWG, 512, SMEM_TOT, stream>>>(whf, wsf, (const uint4*)wpxh, pulse,
                                                  zbias, zdec0, b_lstm,
                                                  W_mlp, b_mlp, scale_w, scale_b, out);
        return;
    }

    const size_t NW = (size_t)HH * H4;
    bool use_bf16 = ws_size >= 3 * NW * sizeof(__hip_bfloat16);
    __hip_bfloat16* wxb = (__hip_bfloat16*)d_ws;
    __hip_bfloat16* whb = wxb + NW;
    __hip_bfloat16* wsb = whb + NW;

    if (use_bf16) {
        prep_weights<<<(int)((NW + 255) / 256), 256, 0, stream>>>(W_x, W_h, wxb, whb, wsb);
        lstm_persist<true><<<BB, 512, 0, stream>>>(
            pulse, bn_gamma, bn_beta, bn_mean, bn_var, W_pe, b_pe, embed,
            W_x, W_h, b_lstm, W_mlp, b_mlp, scale_w, scale_b,
            (const void*)wxb, (const void*)whb, (const void*)wsb, out);
    } else {
        lstm_persist<false><<<BB, 512, 0, stream>>>(
            pulse, bn_gamma, bn_beta, bn_mean, bn_var, W_pe, b_pe, embed,
            W_x, W_h, b_lstm, W_mlp, b_mlp, scale_w, scale_b,
            nullptr, nullptr, nullptr, out);
    }
}

// Round 11
// 5726.489 us; speedup vs baseline: 2.2188x; 2.2188x over previous
//
#include <hip/hip_runtime.h>
#include <hip/hip_bf16.h>
#include <hip/hip_fp16.h>
#include <stdint.h>

#define BB  256
#define TT  512
#define FF  8
#define HH  256
#define H4  1024
#define DEC 35
#define NWG 16
#define MW  16

typedef __attribute__((ext_vector_type(8))) short short8v;
typedef __attribute__((ext_vector_type(4))) float f32x4;

// dynamic-LDS layout (bytes)
#define OFF_PX   0              // f16 wpx table: 1024 n * 16B = 16384
#define OFF_HHI  16384          // h hi A-frags, 2 buffers * 8192
#define OFF_HLO  32768          // h lo A-frags, 2 buffers * 8192
#define OFF_MLP  49152          // sWmlp 512 f32 = 2048
#define OFF_SM   51200          // 6 f32 + pad = 32
#define OFF_HB32 51232          // 16*257*4 = 16448 (decoder MLP staging)
#define SMEM_TOT 67680

__device__ __forceinline__ unsigned short f2bf(float x) {
    unsigned u = __float_as_uint(x);
    u += 0x7fffu + ((u >> 16) & 1u);          // RNE
    return (unsigned short)(u >> 16);
}
__device__ __forceinline__ float bf2f(unsigned s) { return __uint_as_float(s << 16); }
__device__ __forceinline__ float2 h2tof2(unsigned u) {
    __half2 h2 = *reinterpret_cast<const __half2*>(&u);
    return __half22float2(h2);
}
__device__ __forceinline__ float sigf(float x) {
    x = fminf(fmaxf(x, -30.f), 30.f);
    return 1.0f / (1.0f + __expf(-x));
}
__device__ __forceinline__ float tanh_(float x) {
    x = fminf(fmaxf(x, -15.f), 15.f);
    float e = __expf(2.0f * x);
    return (e - 1.0f) / (e + 1.0f);
}

// ===================== prep kernels (proven) =====================

__global__ void prep_consts(const float* __restrict__ W_pe, const float* __restrict__ b_pe,
                            const float* __restrict__ embed, const float* __restrict__ W_x,
                            const float* __restrict__ b_lstm,
                            const float* __restrict__ bn_gamma, const float* __restrict__ bn_beta,
                            const float* __restrict__ bn_mean, const float* __restrict__ bn_var,
                            __half* __restrict__ wpxh, float* __restrict__ zbias,
                            float* __restrict__ zdec0) {
    int n = blockIdx.x * 256 + threadIdx.x;
    float acc[FF];
    #pragma unroll
    for (int f = 0; f < FF; ++f) acc[f] = 0.f;
    float bsum = 0.f, dsum = 0.f;
    for (int m = 0; m < HH; ++m) {
        float wx = W_x[m * H4 + n];
        #pragma unroll
        for (int f = 0; f < FF; ++f) acc[f] = fmaf(W_pe[f * HH + m], wx, acc[f]);
        bsum = fmaf(b_pe[m], wx, bsum);
        dsum = fmaf(embed[m], wx, dsum);
    }
    float zb = b_lstm[n] + bsum;
    #pragma unroll
    for (int f = 0; f < FF; ++f) {
        float s  = bn_gamma[f] * rsqrtf(bn_var[f] + 1e-3f);
        float sh = bn_beta[f] - bn_mean[f] * s;
        wpxh[n * FF + f] = __float2half(s * acc[f]);
        zb = fmaf(sh, acc[f], zb);
    }
    zbias[n] = zb;
    zdec0[n] = b_lstm[n] + dsum;
}

// B-frags: frag[(nt*8+kc)*64+ln][j] = W[k = kc*32 + 8*(ln>>4) + j][nt*16 + (ln&15)]
__global__ void prep_wfrag(const float* __restrict__ W_x, const float* __restrict__ W_h,
                           short8v* __restrict__ whf, short8v* __restrict__ wsf) {
    int nt = blockIdx.x >> 3, kc = blockIdx.x & 7, ln = threadIdx.x;
    int n = nt * 16 + (ln & 15), q = ln >> 4;
    short8v vh, vs;
    #pragma unroll
    for (int j = 0; j < 8; ++j) {
        int k = kc * 32 + q * 8 + j;
        float wh = W_h[k * H4 + n], wx = W_x[k * H4 + n];
        vh[j] = (short)f2bf(wh);
        vs[j] = (short)f2bf(wx + wh);
    }
    whf[blockIdx.x * 64 + ln] = vh;
    wsf[blockIdx.x * 64 + ln] = vs;
}

// ===================== main recurrent kernel =====================
// ROUND-7 STRUCTURE (best known good: 6.0ms, outer-kc, wpx in LDS, dbl-buf h,
// 1 barrier/step) with ONE change: the 8-tile stream chain is split into two
// sequential 4-tile half-chains. Stream dbuf drops 64->32 VGPRs, so the chain
// peak live set is ~96 (<128 budget) instead of ~130 (r7 spilled ~0.5 reg/step,
// 9.5MB/dispatch scratch writes). A-frags re-read per half (+8 ds_read/step,
// negligible). Numerics byte-identical per tile: absmax must repeat 0.0078125.
__global__ __launch_bounds__(512) void lstm_rec9(
    const short8v* __restrict__ whf, const short8v* __restrict__ wsf,
    const uint4* __restrict__ wpx4,
    const float* __restrict__ pulse,
    const float* __restrict__ zbias, const float* __restrict__ zdec0,
    const float* __restrict__ blstm,
    const float* __restrict__ W_mlp, const float* __restrict__ b_mlp,
    const float* __restrict__ scale_w, const float* __restrict__ scale_b,
    float* __restrict__ out) {
    extern __shared__ char smem[];
    uint4*   ldsPX = (uint4*)(smem + OFF_PX);
    short8v* ldsHI = (short8v*)(smem + OFF_HHI);   // [buf][kc][ln]
    short8v* ldsLO = (short8v*)(smem + OFF_HLO);
    float*   sWmlp = (float*)(smem + OFF_MLP);
    float*   sm    = (float*)(smem + OFF_SM);
    float*   hb32  = (float*)(smem + OFF_HB32);

    const int tid = threadIdx.x, g = blockIdx.x;
    const int w = tid >> 6, ln = tid & 63;
    const int col = ln & 15, q = ln >> 4;

    int ntv[8];
    #pragma unroll
    for (int tl = 0; tl < 8; ++tl) ntv[tl] = (tl >> 1) * 16 + 2 * w + (tl & 1);

    // ---- init ----
    for (int i = tid; i < 1024; i += 512) ldsPX[i] = wpx4[i];
    {
        short8v zz = {};
        for (int i = tid; i < 2 * 512; i += 512) { ldsHI[i] = zz; ldsLO[i] = zz; }
    }
    for (int i = tid; i < HH * 2; i += 512) sWmlp[i] = W_mlp[i];
    if (tid < 2) { sm[tid] = b_mlp[tid]; sm[2 + tid] = scale_w[tid]; sm[4 + tid] = scale_b[tid]; }

    float zb[8];
    #pragma unroll
    for (int tl = 0; tl < 8; ++tl) zb[tl] = zbias[ntv[tl] * 16 + col];

    float c[8];
    #pragma unroll
    for (int i = 0; i < 8; ++i) c[i] = 0.f;

    const float* pbase = pulse + (size_t)(g * MW) * TT * FF;
    int rb = 0;
    __syncthreads();

    // 4-tile half-chain: stream dbuf = 4x2 short8v = 32 VGPR
#define CHAIN4(SRC, TL0) do {                                                   \
        short8v ws0[4], ws1[4];                                                 \
        _Pragma("unroll")                                                       \
        for (int i = 0; i < 4; ++i) {                                           \
            ws0[i] = (SRC)[(size_t)(ntv[(TL0) + i] * 8 + 0) * 64 + ln];         \
            ws1[i] = (SRC)[(size_t)(ntv[(TL0) + i] * 8 + 1) * 64 + ln];         \
        }                                                                       \
        _Pragma("unroll")                                                       \
        for (int kc = 0; kc < 8; ++kc) {                                        \
            short8v ah = ldsHI[rb * 512 + kc * 64 + ln];                        \
            short8v al = ldsLO[rb * 512 + kc * 64 + ln];                        \
            if ((kc & 1) == 0) {                                                \
                _Pragma("unroll")                                               \
                for (int i = 0; i < 4; ++i) {                                   \
                    acc[(TL0) + i] = __builtin_amdgcn_mfma_f32_16x16x32_bf16(ah, ws0[i], acc[(TL0) + i], 0, 0, 0); \
                    acc[(TL0) + i] = __builtin_amdgcn_mfma_f32_16x16x32_bf16(al, ws0[i], acc[(TL0) + i], 0, 0, 0); \
                    if (kc + 2 < 8) ws0[i] = (SRC)[(size_t)(ntv[(TL0) + i] * 8 + kc + 2) * 64 + ln]; \
                }                                                               \
            } else {                                                            \
                _Pragma("unroll")                                               \
                for (int i = 0; i < 4; ++i) {                                   \
                    acc[(TL0) + i] = __builtin_amdgcn_mfma_f32_16x16x32_bf16(ah, ws1[i], acc[(TL0) + i], 0, 0, 0); \
                    acc[(TL0) + i] = __builtin_amdgcn_mfma_f32_16x16x32_bf16(al, ws1[i], acc[(TL0) + i], 0, 0, 0); \
                    if (kc + 2 < 8) ws1[i] = (SRC)[(size_t)(ntv[(TL0) + i] * 8 + kc + 2) * 64 + ln]; \
                }                                                               \
            }                                                                   \
        }                                                                       \
    } while (0)

#define GATES_WRITE(WITH_HB32) do {                                             \
        unsigned short* hHIs = (unsigned short*)(smem + OFF_HHI) + (rb ^ 1) * 4096; \
        unsigned short* hLOs = (unsigned short*)(smem + OFF_HLO) + (rb ^ 1) * 4096; \
        _Pragma("unroll")                                                       \
        for (int p = 0; p < 2; ++p)                                             \
            _Pragma("unroll")                                                   \
            for (int r = 0; r < 4; ++r) {                                       \
                float cc = sigf(acc[2 + p][r]) * c[p * 4 + r] + sigf(acc[p][r]) * tanh_(acc[4 + p][r]); \
                c[p * 4 + r] = cc;                                              \
                float hh = sigf(acc[6 + p][r]) * tanh_(cc);                     \
                unsigned short hi = f2bf(hh);                                   \
                float lo = hh - bf2f(hi);                                       \
                int ad = w * 512 + (2 * p + (col >> 3)) * 128 + (4 * q + r) * 8 + (col & 7); \
                hHIs[ad] = hi;                                                  \
                hLOs[ad] = f2bf(lo);                                            \
                if (WITH_HB32) hb32[(4 * q + r) * 257 + (32 * w + 16 * p + col)] = hh; \
            }                                                                   \
    } while (0)

    // ---- encoder: 512 steps, ONE barrier each ----
    for (int t = 0; t < TT; ++t) {
        float4 xc[4][2];
        #pragma unroll
        for (int r = 0; r < 4; ++r) {
            const float* pr = pbase + (size_t)(4 * q + r) * TT * FF + (size_t)t * FF;
            xc[r][0] = ((const float4*)pr)[0];
            xc[r][1] = ((const float4*)pr)[1];
        }
        f32x4 acc[8];
        #pragma unroll
        for (int tl = 0; tl < 8; ++tl) {
            uint4 wp = ldsPX[ntv[tl] * 16 + col];
            float wv[8];
            float2 d;
            d = h2tof2(wp.x); wv[0] = d.x; wv[1] = d.y;
            d = h2tof2(wp.y); wv[2] = d.x; wv[3] = d.y;
            d = h2tof2(wp.z); wv[4] = d.x; wv[5] = d.y;
            d = h2tof2(wp.w); wv[6] = d.x; wv[7] = d.y;
            f32x4 av;
            #pragma unroll
            for (int r = 0; r < 4; ++r) {
                float s = zb[tl];
                s = fmaf(xc[r][0].x, wv[0], s); s = fmaf(xc[r][0].y, wv[1], s);
                s = fmaf(xc[r][0].z, wv[2], s); s = fmaf(xc[r][0].w, wv[3], s);
                s = fmaf(xc[r][1].x, wv[4], s); s = fmaf(xc[r][1].y, wv[5], s);
                s = fmaf(xc[r][1].z, wv[6], s); s = fmaf(xc[r][1].w, wv[7], s);
                av[r] = s;
            }
            acc[tl] = av;
        }
        CHAIN4(whf, 0);
        CHAIN4(whf, 4);
        GATES_WRITE(0);
        __syncthreads();
        rb ^= 1;
    }

    // ---- decoder: 35 steps ----
    float zd0[8], bl[8];
    #pragma unroll
    for (int tl = 0; tl < 8; ++tl) {
        zd0[tl] = zdec0[ntv[tl] * 16 + col];
        bl[tl]  = blstm[ntv[tl] * 16 + col];
    }

    for (int s = 0; s < DEC; ++s) {
        f32x4 acc[8];
        if (s == 0) {
            #pragma unroll
            for (int tl = 0; tl < 8; ++tl) {
                f32x4 av; av[0] = zd0[tl]; av[1] = zd0[tl]; av[2] = zd0[tl]; av[3] = zd0[tl];
                acc[tl] = av;
            }
            CHAIN4(whf, 0);
            CHAIN4(whf, 4);
        } else {
            #pragma unroll
            for (int tl = 0; tl < 8; ++tl) {
                f32x4 av; av[0] = bl[tl]; av[1] = bl[tl]; av[2] = bl[tl]; av[3] = bl[tl];
                acc[tl] = av;
            }
            CHAIN4(wsf, 0);
            CHAIN4(wsf, 4);
        }
        GATES_WRITE(1);
        __syncthreads();

        // MLP head: pred = h@W_mlp + b_mlp; eis = pred*sw + sb
        {
            int m = tid >> 5, j = (tid >> 4) & 1, uc = tid & 15;
            float p2 = 0.f;
            #pragma unroll
            for (int i = 0; i < 16; ++i) {
                int u = i * 16 + uc;
                p2 = fmaf(hb32[m * 257 + u], sWmlp[u * 2 + j], p2);
            }
            p2 += __shfl_down(p2, 8, 16);
            p2 += __shfl_down(p2, 4, 16);
            p2 += __shfl_down(p2, 2, 16);
            p2 += __shfl_down(p2, 1, 16);
            if (uc == 0) {
                float pr = p2 + sm[j];
                out[((size_t)(g * MW + m) * DEC + s) * 2 + j] = pr * sm[2 + j] + sm[4 + j];
            }
        }
        __syncthreads();
        rb ^= 1;
    }
#undef CHAIN4
#undef GATES_WRITE
}

// ===================== fallback (round-2, proven) =====================
__global__ void prep_weights(const float* __restrict__ Wx, const float* __restrict__ Wh,
                             __hip_bfloat16* __restrict__ wxb,
                             __hip_bfloat16* __restrict__ whb,
                             __hip_bfloat16* __restrict__ wsb) {
    int i = blockIdx.x * 256 + threadIdx.x;
    if (i < HH * H4) {
        float x = Wx[i], h = Wh[i];
        wxb[i] = __float2bfloat16(x);
        whb[i] = __float2bfloat16(h);
        wsb[i] = __float2bfloat16(x + h);
    }
}

template<bool BF16W>
__device__ __forceinline__ void matvec2(const void* __restrict__ W,
                                        const float* __restrict__ vec,
                                        int tid, float& z0, float& z1) {
    if constexpr (BF16W) {
        const uint32_t* Wp = (const uint32_t*)W;
        #pragma unroll 8
        for (int k = 0; k < HH; ++k) {
            uint32_t w = Wp[(size_t)k * (H4 / 2) + tid];
            float s = vec[k];
            union { uint32_t u; float f; } lo, hi;
            lo.u = w << 16;
            hi.u = w & 0xffff0000u;
            z0 = fmaf(s, lo.f, z0);
            z1 = fmaf(s, hi.f, z1);
        }
    } else {
        const float2* Wp = (const float2*)W;
        #pragma unroll 8
        for (int k = 0; k < HH; ++k) {
            float2 w = Wp[(size_t)k * (H4 / 2) + tid];
            float s = vec[k];
            z0 = fmaf(s, w.x, z0);
            z1 = fmaf(s, w.y, z1);
        }
    }
}

__device__ __forceinline__ float sigmoidf_(float x) { return 1.0f / (1.0f + expf(-x)); }

template<bool BF16W>
__global__ __launch_bounds__(512)
void lstm_persist(const float* __restrict__ pulse,
                  const float* __restrict__ bn_gamma, const float* __restrict__ bn_beta,
                  const float* __restrict__ bn_mean, const float* __restrict__ bn_var,
                  const float* __restrict__ W_pe, const float* __restrict__ b_pe,
                  const float* __restrict__ embed,
                  const float* __restrict__ W_x, const float* __restrict__ W_h,
                  const float* __restrict__ b_lstm,
                  const float* __restrict__ W_mlp, const float* __restrict__ b_mlp,
                  const float* __restrict__ scale_w, const float* __restrict__ scale_b,
                  const void* __restrict__ WxQ, const void* __restrict__ WhQ,
                  const void* __restrict__ WsQ,
                  float* __restrict__ out) {
    __shared__ float sWpe2[FF * HH];
    __shared__ float sbpe2[HH];
    __shared__ float sbl[H4];
    __shared__ float sWmlp[HH * 2];
    __shared__ float sbuf[HH];
    __shared__ float hbuf[HH];
    __shared__ float cbuf[HH];
    __shared__ float zbuf[H4];
    __shared__ float bnsc[FF], bnsh[FF];
    __shared__ float smisc[6];

    const int tid = threadIdx.x;
    const int bb  = blockIdx.x;

    if (tid < FF) {
        float s = bn_gamma[tid] * rsqrtf(bn_var[tid] + 1e-3f);
        bnsc[tid] = s;
        bnsh[tid] = bn_beta[tid] - bn_mean[tid] * s;
    }
    if (tid < 2) {
        smisc[tid]     = b_mlp[tid];
        smisc[2 + tid] = scale_w[tid];
        smisc[4 + tid] = scale_b[tid];
    }
    for (int i = tid; i < H4; i += 512) sbl[i] = b_lstm[i];
    for (int i = tid; i < 2 * HH; i += 512) sWmlp[i] = W_mlp[i];
    for (int i = tid; i < HH; i += 512) { hbuf[i] = 0.f; cbuf[i] = 0.f; }
    __syncthreads();
    for (int i = tid; i < FF * HH; i += 512) sWpe2[i] = W_pe[i] * bnsc[i / HH];
    for (int i = tid; i < HH; i += 512) {
        float a = b_pe[i];
        #pragma unroll
        for (int f = 0; f < FF; ++f) a = fmaf(bnsh[f], W_pe[f * HH + i], a);
        sbpe2[i] = a;
    }
    __syncthreads();
    if (tid >= HH && tid < 2 * HH) {
        int u = tid - HH;
        const float* pr = pulse + (size_t)bb * TT * FF;
        float acc = sbpe2[u];
        #pragma unroll
        for (int f = 0; f < FF; ++f) acc = fmaf(pr[f], sWpe2[f * HH + u], acc);
        sbuf[u] = acc;
    }
    __syncthreads();

    for (int t = 0; t < TT; ++t) {
        float z0 = sbl[2 * tid], z1 = sbl[2 * tid + 1];
        if constexpr (BF16W) {
            matvec2<true>(WxQ, sbuf, tid, z0, z1);
            matvec2<true>(WhQ, hbuf, tid, z0, z1);
        } else {
            matvec2<false>(W_x, sbuf, tid, z0, z1);
            matvec2<false>(W_h, hbuf, tid, z0, z1);
        }
        zbuf[2 * tid] = z0; zbuf[2 * tid + 1] = z1;
        __syncthreads();
        if (tid < HH) {
            float iv = zbuf[tid], fv = zbuf[tid + HH];
            float gv = zbuf[tid + 2 * HH], ov = zbuf[tid + 3 * HH];
            float c = sigmoidf_(fv) * cbuf[tid] + sigmoidf_(iv) * tanhf(gv);
            cbuf[tid] = c;
            hbuf[tid] = sigmoidf_(ov) * tanhf(c);
        } else if (tid < 2 * HH) {
            int u = tid - HH;
            float acc;
            if (t + 1 < TT) {
                const float* pr = pulse + ((size_t)bb * TT + (t + 1)) * FF;
                acc = sbpe2[u];
                #pragma unroll
                for (int f = 0; f < FF; ++f) acc = fmaf(pr[f], sWpe2[f * HH + u], acc);
            } else {
                acc = embed[u];
            }
            sbuf[u] = acc;
        }
        __syncthreads();
    }

    for (int s = 0; s < DEC; ++s) {
        float z0 = sbl[2 * tid], z1 = sbl[2 * tid + 1];
        if (s == 0) {
            if constexpr (BF16W) {
                matvec2<true>(WxQ, sbuf, tid, z0, z1);
                matvec2<true>(WhQ, hbuf, tid, z0, z1);
            } else {
                matvec2<false>(W_x, sbuf, tid, z0, z1);
                matvec2<false>(W_h, hbuf, tid, z0, z1);
            }
        } else {
            if constexpr (BF16W) {
                matvec2<true>(WsQ, hbuf, tid, z0, z1);
            } else {
                matvec2<false>(W_x, hbuf, tid, z0, z1);
                matvec2<false>(W_h, hbuf, tid, z0, z1);
            }
        }
        zbuf[2 * tid] = z0; zbuf[2 * tid + 1] = z1;
        __syncthreads();
        if (tid < HH) {
            float iv = zbuf[tid], fv = zbuf[tid + HH];
            float gv = zbuf[tid + 2 * HH], ov = zbuf[tid + 3 * HH];
            float c = sigmoidf_(fv) * cbuf[tid] + sigmoidf_(iv) * tanhf(gv);
            cbuf[tid] = c;
            hbuf[tid] = sigmoidf_(ov) * tanhf(c);
        }
        __syncthreads();
        if (tid < 128) {
            int j = tid >> 6, lane = tid & 63;
            float p = 0.f;
            #pragma unroll
            for (int u = lane; u < HH; u += 64) p = fmaf(hbuf[u], sWmlp[u * 2 + j], p);
            p += __shfl_down(p, 32); p += __shfl_down(p, 16); p += __shfl_down(p, 8);
            p += __shfl_down(p, 4);  p += __shfl_down(p, 2);  p += __shfl_down(p, 1);
            if (lane == 0) {
                float pr2 = p + smisc[j];
                out[((size_t)bb * DEC + s) * 2 + j] = pr2 * smisc[2 + j] + smisc[4 + j];
            }
        }
        __syncthreads();
    }
}

extern "C" void kernel_launch(void* const* d_in, const int* in_sizes, int n_in,
                              void* d_out, int out_size, void* d_ws, size_t ws_size,
                              hipStream_t stream) {
    const float* pulse    = (const float*)d_in[0];
    const float* bn_gamma = (const float*)d_in[1];
    const float* bn_beta  = (const float*)d_in[2];
    const float* bn_mean  = (const float*)d_in[3];
    const float* bn_var   = (const float*)d_in[4];
    const float* W_pe     = (const float*)d_in[5];
    const float* b_pe     = (const float*)d_in[6];
    const float* embed    = (const float*)d_in[7];
    const float* W_x      = (const float*)d_in[8];
    const float* W_h      = (const float*)d_in[9];
    const float* b_lstm   = (const float*)d_in[10];
    const float* W_mlp    = (const float*)d_in[11];
    const float* b_mlp    = (const float*)d_in[12];
    const float* scale_w  = (const float*)d_in[13];
    const float* scale_b  = (const float*)d_in[14];
    float* out = (float*)d_out;

    // ws layout: whf 512K | wsf 512K | wpxh 16K | zbias 4K | zdec0 4K
    const size_t SZ_WF  = (size_t)64 * 8 * 64 * 16;     // 524288
    const size_t SZ_PXH = (size_t)H4 * FF * 2;          // 16384
    const size_t needA = 2 * SZ_WF + SZ_PXH + 2 * (size_t)H4 * 4;

    if (ws_size >= needA) {
        short8v* whf   = (short8v*)d_ws;
        short8v* wsf   = (short8v*)((char*)d_ws + SZ_WF);
        __half*  wpxh  = (__half*)((char*)d_ws + 2 * SZ_WF);
        float*   zbias = (float*)((char*)d_ws + 2 * SZ_WF + SZ_PXH);
        float*   zdec0 = zbias + H4;

        hipFuncSetAttribute((const void*)lstm_rec9,
                            hipFuncAttributeMaxDynamicSharedMemorySize, SMEM_TOT);

        prep_consts<<<4, 256, 0, stream>>>(W_pe, b_pe, embed, W_x, b_lstm,
                                           bn_gamma, bn_beta, bn_mean, bn_var,
                                           wpxh, zbias, zdec0);
        prep_wfrag<<<512, 64, 0, stream>>>(W_x, W_h, whf, wsf);
        lstm_rec9<<<NWG, 512, SMEM_TOT, stream>>>(whf, wsf, (const uint4*)wpxh, pulse,
                                                  zbias, zdec0, b_lstm,
                                                  W_mlp, b_mlp, scale_w, scale_b, out);
        return;
    }

    const size_t NW = (size_t)HH * H4;
    bool use_bf16 = ws_size >= 3 * NW * sizeof(__hip_bfloat16);
    __hip_bfloat16* wxb = (__hip_bfloat16*)d_ws;
    __hip_bfloat16* whb = wxb + NW;
    __hip_bfloat16* wsb = whb + NW;

    if (use_bf16) {
        prep_weights<<<(int)((NW + 255) / 256), 256, 0, stream>>>(W_x, W_h, wxb, whb, wsb);
        lstm_persist<true><<<BB, 512, 0, stream>>>(
            pulse, bn_gamma, bn_beta, bn_mean, bn_var, W_pe, b_pe, embed,
            W_x, W_h, b_lstm, W_mlp, b_mlp, scale_w, scale_b,
            (const void*)wxb, (const void*)whb, (const void*)wsb, out);
    } else {
        lstm_persist<false><<<BB, 512, 0, stream>>>(
            pulse, bn_gamma, bn_beta, bn_mean, bn_var, W_pe, b_pe, embed,
            W_x, W_h, b_lstm, W_mlp, b_mlp, scale_w, scale_b,
            nullptr, nullptr, nullptr, out);
    }
}

// Round 12
// 5391.465 us; speedup vs baseline: 2.3567x; 1.0621x over previous
//
#include <hip/hip_runtime.h>
#include <hip/hip_bf16.h>
#include <hip/hip_fp16.h>
#include <stdint.h>

#define BB  256
#define TT  512
#define FF  8
#define HH  256
#define H4  1024
#define DEC 35
#define NWG 16
#define MW  16

typedef __attribute__((ext_vector_type(8))) short short8v;
typedef __attribute__((ext_vector_type(4))) float f32x4;

// dynamic-LDS layout (bytes)
#define OFF_WPX  0              // zx B-frags: 64 tiles * 64 lanes * 16B = 65536
#define OFF_HHI  65536          // h hi A-frags, 2 buffers * 8192 = 16384
#define OFF_HLO  81920          // h lo A-frags, 2 buffers * 8192 = 16384
#define OFF_MLP  98304          // sWmlp 512 f32 = 2048
#define OFF_SM   100352         // 6 f32 + pad = 32
#define OFF_HB32 100384         // 16*257*4 = 16448 (decoder MLP staging)
#define SMEM_TOT 116832

__device__ __forceinline__ unsigned short f2bf(float x) {
    unsigned u = __float_as_uint(x);
    u += 0x7fffu + ((u >> 16) & 1u);          // RNE
    return (unsigned short)(u >> 16);
}
__device__ __forceinline__ float bf2f(unsigned s) { return __uint_as_float(s << 16); }
__device__ __forceinline__ float sigf(float x) {
    x = fminf(fmaxf(x, -30.f), 30.f);
    return 1.0f / (1.0f + __expf(-x));
}
__device__ __forceinline__ float tanh_(float x) {
    x = fminf(fmaxf(x, -15.f), 15.f);
    float e = __expf(2.0f * x);
    return (e - 1.0f) / (e + 1.0f);
}

// ===================== prep kernels =====================

// Wpx32[f][n] = bnscale[f] * (W_pe @ W_x)[f][n]  (fp32)
// zbias[n]  = b_lstm + b_pe@W_x + bnshift@(W_pe@W_x)
// zdec0[n]  = b_lstm + embed@W_x
__global__ void prep_consts(const float* __restrict__ W_pe, const float* __restrict__ b_pe,
                            const float* __restrict__ embed, const float* __restrict__ W_x,
                            const float* __restrict__ b_lstm,
                            const float* __restrict__ bn_gamma, const float* __restrict__ bn_beta,
                            const float* __restrict__ bn_mean, const float* __restrict__ bn_var,
                            float* __restrict__ Wpx32, float* __restrict__ zbias,
                            float* __restrict__ zdec0) {
    int n = blockIdx.x * 256 + threadIdx.x;
    float acc[FF];
    #pragma unroll
    for (int f = 0; f < FF; ++f) acc[f] = 0.f;
    float bsum = 0.f, dsum = 0.f;
    for (int m = 0; m < HH; ++m) {
        float wx = W_x[m * H4 + n];
        #pragma unroll
        for (int f = 0; f < FF; ++f) acc[f] = fmaf(W_pe[f * HH + m], wx, acc[f]);
        bsum = fmaf(b_pe[m], wx, bsum);
        dsum = fmaf(embed[m], wx, dsum);
    }
    float zb = b_lstm[n] + bsum;
    #pragma unroll
    for (int f = 0; f < FF; ++f) {
        float s  = bn_gamma[f] * rsqrtf(bn_var[f] + 1e-3f);
        float sh = bn_beta[f] - bn_mean[f] * s;
        Wpx32[f * H4 + n] = s * acc[f];
        zb = fmaf(sh, acc[f], zb);
    }
    zbias[n] = zb;
    zdec0[n] = b_lstm[n] + dsum;
}

// B-frags: frag[(nt*8+kc)*64+ln][j] = W[k = kc*32 + 8*(ln>>4) + j][nt*16 + (ln&15)]
__global__ void prep_wfrag(const float* __restrict__ W_x, const float* __restrict__ W_h,
                           short8v* __restrict__ whf, short8v* __restrict__ wsf) {
    int nt = blockIdx.x >> 3, kc = blockIdx.x & 7, ln = threadIdx.x;
    int n = nt * 16 + (ln & 15), q = ln >> 4;
    short8v vh, vs;
    #pragma unroll
    for (int j = 0; j < 8; ++j) {
        int k = kc * 32 + q * 8 + j;
        float wh = W_h[k * H4 + n], wx = W_x[k * H4 + n];
        vh[j] = (short)f2bf(wh);
        vs[j] = (short)f2bf(wx + wh);
    }
    whf[blockIdx.x * 64 + ln] = vh;
    wsf[blockIdx.x * 64 + ln] = vs;
}

// zx B-frags: K=32 packed as [Whi | Whi | Wlo | Wlo] across k-quarters.
// Pairs with A packed as [ph | pl | ph | pl] -> one MFMA gives
// (ph+pl)*(Whi+Wlo) = fp32-accurate pulse @ Wpx.
__global__ void prep_wpxf(const float* __restrict__ Wpx32, short8v* __restrict__ wpxf) {
    int nt = blockIdx.x, ln = threadIdx.x;
    int n = nt * 16 + (ln & 15), qq = ln >> 4;
    short8v v;
    #pragma unroll
    for (int j = 0; j < 8; ++j) {
        float wv = Wpx32[j * H4 + n];
        unsigned short hi = f2bf(wv);
        v[j] = (qq < 2) ? (short)hi : (short)f2bf(wv - bf2f(hi));
    }
    wpxf[nt * 64 + ln] = v;
}

// ===================== main recurrent kernel =====================
// ROUND-11 STRUCTURE (best: 5.73ms; outer-kc, two 4-tile half-chains, dbl-buf
// split-h, 1 barrier/step) with ONE change: the scalar fp32 zx block (~300
// VALU/wave/step, the largest per-CU VALU consumer at 35% busy) is replaced
// by ONE MFMA per tile via K-packing (A=[ph|pl|ph|pl], B=[Whi|Whi|Wlo|Wlo]),
// numerically >= the old f16-Wpx path. wpxf lives in LDS (64KB).
__global__ __launch_bounds__(512) void lstm_rec10(
    const short8v* __restrict__ whf, const short8v* __restrict__ wsf,
    const short8v* __restrict__ wpxf,
    const float* __restrict__ pulse,
    const float* __restrict__ zbias, const float* __restrict__ zdec0,
    const float* __restrict__ blstm,
    const float* __restrict__ W_mlp, const float* __restrict__ b_mlp,
    const float* __restrict__ scale_w, const float* __restrict__ scale_b,
    float* __restrict__ out) {
    extern __shared__ char smem[];
    short8v* ldsWPX = (short8v*)(smem + OFF_WPX);
    short8v* ldsHI  = (short8v*)(smem + OFF_HHI);   // [buf][kc][ln]
    short8v* ldsLO  = (short8v*)(smem + OFF_HLO);
    float*   sWmlp  = (float*)(smem + OFF_MLP);
    float*   sm     = (float*)(smem + OFF_SM);
    float*   hb32   = (float*)(smem + OFF_HB32);

    const int tid = threadIdx.x, g = blockIdx.x;
    const int w = tid >> 6, ln = tid & 63;
    const int col = ln & 15, q = ln >> 4;

    int ntv[8];
    #pragma unroll
    for (int tl = 0; tl < 8; ++tl) ntv[tl] = (tl >> 1) * 16 + 2 * w + (tl & 1);

    // ---- init ----
    for (int i = tid; i < 64 * 64; i += 512) ldsWPX[i] = wpxf[i];
    {
        short8v zz = {};
        for (int i = tid; i < 2 * 512; i += 512) { ldsHI[i] = zz; ldsLO[i] = zz; }
    }
    for (int i = tid; i < HH * 2; i += 512) sWmlp[i] = W_mlp[i];
    if (tid < 2) { sm[tid] = b_mlp[tid]; sm[2 + tid] = scale_w[tid]; sm[4 + tid] = scale_b[tid]; }

    float zb[8];
    #pragma unroll
    for (int tl = 0; tl < 8; ++tl) zb[tl] = zbias[ntv[tl] * 16 + col];

    float c[8];
    #pragma unroll
    for (int i = 0; i < 8; ++i) c[i] = 0.f;

    // per-lane pulse row pointer: A row = batch = ln&15 (advances 8 floats/step)
    const float* ppt = pulse + ((size_t)(g * MW + (ln & 15)) * TT) * FF;
    const int lohalf = q & 1;   // k-quarters 1,3 carry pulse-lo
    int rb = 0;
    __syncthreads();

    // 4-tile half-chain: stream dbuf = 4x2 short8v = 32 VGPR (r11-proven)
#define CHAIN4(SRC, TL0) do {                                                   \
        short8v ws0[4], ws1[4];                                                 \
        _Pragma("unroll")                                                       \
        for (int i = 0; i < 4; ++i) {                                           \
            ws0[i] = (SRC)[(size_t)(ntv[(TL0) + i] * 8 + 0) * 64 + ln];         \
            ws1[i] = (SRC)[(size_t)(ntv[(TL0) + i] * 8 + 1) * 64 + ln];         \
        }                                                                       \
        _Pragma("unroll")                                                       \
        for (int kc = 0; kc < 8; ++kc) {                                        \
            short8v ah = ldsHI[rb * 512 + kc * 64 + ln];                        \
            short8v al = ldsLO[rb * 512 + kc * 64 + ln];                        \
            if ((kc & 1) == 0) {                                                \
                _Pragma("unroll")                                               \
                for (int i = 0; i < 4; ++i) {                                   \
                    acc[(TL0) + i] = __builtin_amdgcn_mfma_f32_16x16x32_bf16(ah, ws0[i], acc[(TL0) + i], 0, 0, 0); \
                    acc[(TL0) + i] = __builtin_amdgcn_mfma_f32_16x16x32_bf16(al, ws0[i], acc[(TL0) + i], 0, 0, 0); \
                    if (kc + 2 < 8) ws0[i] = (SRC)[(size_t)(ntv[(TL0) + i] * 8 + kc + 2) * 64 + ln]; \
                }                                                               \
            } else {                                                            \
                _Pragma("unroll")                                               \
                for (int i = 0; i < 4; ++i) {                                   \
                    acc[(TL0) + i] = __builtin_amdgcn_mfma_f32_16x16x32_bf16(ah, ws1[i], acc[(TL0) + i], 0, 0, 0); \
                    acc[(TL0) + i] = __builtin_amdgcn_mfma_f32_16x16x32_bf16(al, ws1[i], acc[(TL0) + i], 0, 0, 0); \
                    if (kc + 2 < 8) ws1[i] = (SRC)[(size_t)(ntv[(TL0) + i] * 8 + kc + 2) * 64 + ln]; \
                }                                                               \
            }                                                                   \
        }                                                                       \
    } while (0)

#define GATES_WRITE(WITH_HB32) do {                                             \
        unsigned short* hHIs = (unsigned short*)(smem + OFF_HHI) + (rb ^ 1) * 4096; \
        unsigned short* hLOs = (unsigned short*)(smem + OFF_HLO) + (rb ^ 1) * 4096; \
        _Pragma("unroll")                                                       \
        for (int p = 0; p < 2; ++p)                                             \
            _Pragma("unroll")                                                   \
            for (int r = 0; r < 4; ++r) {                                       \
                float cc = sigf(acc[2 + p][r]) * c[p * 4 + r] + sigf(acc[p][r]) * tanh_(acc[4 + p][r]); \
                c[p * 4 + r] = cc;                                              \
                float hh = sigf(acc[6 + p][r]) * tanh_(cc);                     \
                unsigned short hi = f2bf(hh);                                   \
                float lo = hh - bf2f(hi);                                       \
                int ad = w * 512 + (2 * p + (col >> 3)) * 128 + (4 * q + r) * 8 + (col & 7); \
                hHIs[ad] = hi;                                                  \
                hLOs[ad] = f2bf(lo);                                            \
                if (WITH_HB32) hb32[(4 * q + r) * 257 + (32 * w + 16 * p + col)] = hh; \
            }                                                                   \
    } while (0)

    // ---- encoder: 512 steps, ONE barrier each ----
    for (int t = 0; t < TT; ++t) {
        // A-pack: [ph|pl|ph|pl] across k-quarters (this lane provides its quarter)
        float4 p0 = ((const float4*)ppt)[0];
        float4 p1 = ((const float4*)ppt)[1];
        ppt += FF;
        float pv[8];
        pv[0] = p0.x; pv[1] = p0.y; pv[2] = p0.z; pv[3] = p0.w;
        pv[4] = p1.x; pv[5] = p1.y; pv[6] = p1.z; pv[7] = p1.w;
        short8v apack;
        #pragma unroll
        for (int j = 0; j < 8; ++j) {
            unsigned short hi = f2bf(pv[j]);
            apack[j] = lohalf ? (short)f2bf(pv[j] - bf2f(hi)) : (short)hi;
        }

        // zx: ONE MFMA per tile (B = wpxf in LDS), acc init = zbias
        f32x4 acc[8];
        #pragma unroll
        for (int tl = 0; tl < 8; ++tl) {
            f32x4 av; av[0] = zb[tl]; av[1] = zb[tl]; av[2] = zb[tl]; av[3] = zb[tl];
            short8v bw = ldsWPX[ntv[tl] * 64 + ln];
            acc[tl] = __builtin_amdgcn_mfma_f32_16x16x32_bf16(apack, bw, av, 0, 0, 0);
        }
        CHAIN4(whf, 0);
        CHAIN4(whf, 4);
        GATES_WRITE(0);
        __syncthreads();
        rb ^= 1;
    }

    // ---- decoder: 35 steps ----
    float zd0[8], bl[8];
    #pragma unroll
    for (int tl = 0; tl < 8; ++tl) {
        zd0[tl] = zdec0[ntv[tl] * 16 + col];
        bl[tl]  = blstm[ntv[tl] * 16 + col];
    }

    for (int s = 0; s < DEC; ++s) {
        f32x4 acc[8];
        if (s == 0) {
            #pragma unroll
            for (int tl = 0; tl < 8; ++tl) {
                f32x4 av; av[0] = zd0[tl]; av[1] = zd0[tl]; av[2] = zd0[tl]; av[3] = zd0[tl];
                acc[tl] = av;
            }
            CHAIN4(whf, 0);
            CHAIN4(whf, 4);
        } else {
            #pragma unroll
            for (int tl = 0; tl < 8; ++tl) {
                f32x4 av; av[0] = bl[tl]; av[1] = bl[tl]; av[2] = bl[tl]; av[3] = bl[tl];
                acc[tl] = av;
            }
            CHAIN4(wsf, 0);
            CHAIN4(wsf, 4);
        }
        GATES_WRITE(1);
        __syncthreads();

        // MLP head: pred = h@W_mlp + b_mlp; eis = pred*sw + sb
        {
            int m = tid >> 5, j = (tid >> 4) & 1, uc = tid & 15;
            float p2 = 0.f;
            #pragma unroll
            for (int i = 0; i < 16; ++i) {
                int u = i * 16 + uc;
                p2 = fmaf(hb32[m * 257 + u], sWmlp[u * 2 + j], p2);
            }
            p2 += __shfl_down(p2, 8, 16);
            p2 += __shfl_down(p2, 4, 16);
            p2 += __shfl_down(p2, 2, 16);
            p2 += __shfl_down(p2, 1, 16);
            if (uc == 0) {
                float pr = p2 + sm[j];
                out[((size_t)(g * MW + m) * DEC + s) * 2 + j] = pr * sm[2 + j] + sm[4 + j];
            }
        }
        __syncthreads();
        rb ^= 1;
    }
#undef CHAIN4
#undef GATES_WRITE
}

// ===================== fallback (round-2, proven) =====================
__global__ void prep_weights(const float* __restrict__ Wx, const float* __restrict__ Wh,
                             __hip_bfloat16* __restrict__ wxb,
                             __hip_bfloat16* __restrict__ whb,
                             __hip_bfloat16* __restrict__ wsb) {
    int i = blockIdx.x * 256 + threadIdx.x;
    if (i < HH * H4) {
        float x = Wx[i], h = Wh[i];
        wxb[i] = __float2bfloat16(x);
        whb[i] = __float2bfloat16(h);
        wsb[i] = __float2bfloat16(x + h);
    }
}

template<bool BF16W>
__device__ __forceinline__ void matvec2(const void* __restrict__ W,
                                        const float* __restrict__ vec,
                                        int tid, float& z0, float& z1) {
    if constexpr (BF16W) {
        const uint32_t* Wp = (const uint32_t*)W;
        #pragma unroll 8
        for (int k = 0; k < HH; ++k) {
            uint32_t w = Wp[(size_t)k * (H4 / 2) + tid];
            float s = vec[k];
            union { uint32_t u; float f; } lo, hi;
            lo.u = w << 16;
            hi.u = w & 0xffff0000u;
            z0 = fmaf(s, lo.f, z0);
            z1 = fmaf(s, hi.f, z1);
        }
    } else {
        const float2* Wp = (const float2*)W;
        #pragma unroll 8
        for (int k = 0; k < HH; ++k) {
            float2 w = Wp[(size_t)k * (H4 / 2) + tid];
            float s = vec[k];
            z0 = fmaf(s, w.x, z0);
            z1 = fmaf(s, w.y, z1);
        }
    }
}

__device__ __forceinline__ float sigmoidf_(float x) { return 1.0f / (1.0f + expf(-x)); }

template<bool BF16W>
__global__ __launch_bounds__(512)
void lstm_persist(const float* __restrict__ pulse,
                  const float* __restrict__ bn_gamma, const float* __restrict__ bn_beta,
                  const float* __restrict__ bn_mean, const float* __restrict__ bn_var,
                  const float* __restrict__ W_pe, const float* __restrict__ b_pe,
                  const float* __restrict__ embed,
                  const float* __restrict__ W_x, const float* __restrict__ W_h,
                  const float* __restrict__ b_lstm,
                  const float* __restrict__ W_mlp, const float* __restrict__ b_mlp,
                  const float* __restrict__ scale_w, const float* __restrict__ scale_b,
                  const void* __restrict__ WxQ, const void* __restrict__ WhQ,
                  const void* __restrict__ WsQ,
                  float* __restrict__ out) {
    __shared__ float sWpe2[FF * HH];
    __shared__ float sbpe2[HH];
    __shared__ float sbl[H4];
    __shared__ float sWmlp[HH * 2];
    __shared__ float sbuf[HH];
    __shared__ float hbuf[HH];
    __shared__ float cbuf[HH];
    __shared__ float zbuf[H4];
    __shared__ float bnsc[FF], bnsh[FF];
    __shared__ float smisc[6];

    const int tid = threadIdx.x;
    const int bb  = blockIdx.x;

    if (tid < FF) {
        float s = bn_gamma[tid] * rsqrtf(bn_var[tid] + 1e-3f);
        bnsc[tid] = s;
        bnsh[tid] = bn_beta[tid] - bn_mean[tid] * s;
    }
    if (tid < 2) {
        smisc[tid]     = b_mlp[tid];
        smisc[2 + tid] = scale_w[tid];
        smisc[4 + tid] = scale_b[tid];
    }
    for (int i = tid; i < H4; i += 512) sbl[i] = b_lstm[i];
    for (int i = tid; i < 2 * HH; i += 512) sWmlp[i] = W_mlp[i];
    for (int i = tid; i < HH; i += 512) { hbuf[i] = 0.f; cbuf[i] = 0.f; }
    __syncthreads();
    for (int i = tid; i < FF * HH; i += 512) sWpe2[i] = W_pe[i] * bnsc[i / HH];
    for (int i = tid; i < HH; i += 512) {
        float a = b_pe[i];
        #pragma unroll
        for (int f = 0; f < FF; ++f) a = fmaf(bnsh[f], W_pe[f * HH + i], a);
        sbpe2[i] = a;
    }
    __syncthreads();
    if (tid >= HH && tid < 2 * HH) {
        int u = tid - HH;
        const float* pr = pulse + (size_t)bb * TT * FF;
        float acc = sbpe2[u];
        #pragma unroll
        for (int f = 0; f < FF; ++f) acc = fmaf(pr[f], sWpe2[f * HH + u], acc);
        sbuf[u] = acc;
    }
    __syncthreads();

    for (int t = 0; t < TT; ++t) {
        float z0 = sbl[2 * tid], z1 = sbl[2 * tid + 1];
        if constexpr (BF16W) {
            matvec2<true>(WxQ, sbuf, tid, z0, z1);
            matvec2<true>(WhQ, hbuf, tid, z0, z1);
        } else {
            matvec2<false>(W_x, sbuf, tid, z0, z1);
            matvec2<false>(W_h, hbuf, tid, z0, z1);
        }
        zbuf[2 * tid] = z0; zbuf[2 * tid + 1] = z1;
        __syncthreads();
        if (tid < HH) {
            float iv = zbuf[tid], fv = zbuf[tid + HH];
            float gv = zbuf[tid + 2 * HH], ov = zbuf[tid + 3 * HH];
            float c = sigmoidf_(fv) * cbuf[tid] + sigmoidf_(iv) * tanhf(gv);
            cbuf[tid] = c;
            hbuf[tid] = sigmoidf_(ov) * tanhf(c);
        } else if (tid < 2 * HH) {
            int u = tid - HH;
            float acc;
            if (t + 1 < TT) {
                const float* pr = pulse + ((size_t)bb * TT + (t + 1)) * FF;
                acc = sbpe2[u];
                #pragma unroll
                for (int f = 0; f < FF; ++f) acc = fmaf(pr[f], sWpe2[f * HH + u], acc);
            } else {
                acc = embed[u];
            }
            sbuf[u] = acc;
        }
        __syncthreads();
    }

    for (int s = 0; s < DEC; ++s) {
        float z0 = sbl[2 * tid], z1 = sbl[2 * tid + 1];
        if (s == 0) {
            if constexpr (BF16W) {
                matvec2<true>(WxQ, sbuf, tid, z0, z1);
                matvec2<true>(WhQ, hbuf, tid, z0, z1);
            } else {
                matvec2<false>(W_x, sbuf, tid, z0, z1);
                matvec2<false>(W_h, hbuf, tid, z0, z1);
            }
        } else {
            if constexpr (BF16W) {
                matvec2<true>(WsQ, hbuf, tid, z0, z1);
            } else {
                matvec2<false>(W_x, hbuf, tid, z0, z1);
                matvec2<false>(W_h, hbuf, tid, z0, z1);
            }
        }
        zbuf[2 * tid] = z0; zbuf[2 * tid + 1] = z1;
        __syncthreads();
        if (tid < HH) {
            float iv = zbuf[tid], fv = zbuf[tid + HH];
            float gv = zbuf[tid + 2 * HH], ov = zbuf[tid + 3 * HH];
            float c = sigmoidf_(fv) * cbuf[tid] + sigmoidf_(iv) * tanhf(gv);
            cbuf[tid] = c;
            hbuf[tid] = sigmoidf_(ov) * tanhf(c);
        }
        __syncthreads();
        if (tid < 128) {
            int j = tid >> 6, lane = tid & 63;
            float p = 0.f;
            #pragma unroll
            for (int u = lane; u < HH; u += 64) p = fmaf(hbuf[u], sWmlp[u * 2 + j], p);
            p += __shfl_down(p, 32); p += __shfl_down(p, 16); p += __shfl_down(p, 8);
            p += __shfl_down(p, 4);  p += __shfl_down(p, 2);  p += __shfl_down(p, 1);
            if (lane == 0) {
                float pr2 = p + smisc[j];
                out[((size_t)bb * DEC + s) * 2 + j] = pr2 * smisc[2 + j] + smisc[4 + j];
            }
        }
        __syncthreads();
    }
}

extern "C" void kernel_launch(void* const* d_in, const int* in_sizes, int n_in,
                              void* d_out, int out_size, void* d_ws, size_t ws_size,
                              hipStream_t stream) {
    const float* pulse    = (const float*)d_in[0];
    const float* bn_gamma = (const float*)d_in[1];
    const float* bn_beta  = (const float*)d_in[2];
    const float* bn_mean  = (const float*)d_in[3];
    const float* bn_var   = (const float*)d_in[4];
    const float* W_pe     = (const float*)d_in[5];
    const float* b_pe     = (const float*)d_in[6];
    const float* embed    = (const float*)d_in[7];
    const float* W_x      = (const float*)d_in[8];
    const float* W_h      = (const float*)d_in[9];
    const float* b_lstm   = (const float*)d_in[10];
    const float* W_mlp    = (const float*)d_in[11];
    const float* b_mlp    = (const float*)d_in[12];
    const float* scale_w  = (const float*)d_in[13];
    const float* scale_b  = (const float*)d_in[14];
    float* out = (float*)d_out;

    // ws layout: whf 512K | wsf 512K | wpxf 64K | Wpx32 32K | zbias 4K | zdec0 4K
    const size_t SZ_WF   = (size_t)64 * 8 * 64 * 16;     // 524288
    const size_t SZ_PXF  = (size_t)64 * 64 * 16;         // 65536
    const size_t SZ_PX32 = (size_t)FF * H4 * 4;          // 32768
    const size_t needA = 2 * SZ_WF + SZ_PXF + SZ_PX32 + 2 * (size_t)H4 * 4;

    if (ws_size >= needA) {
        short8v* whf   = (short8v*)d_ws;
        short8v* wsf   = (short8v*)((char*)d_ws + SZ_WF);
        short8v* wpxf  = (short8v*)((char*)d_ws + 2 * SZ_WF);
        float*   Wpx32 = (float*)((char*)d_ws + 2 * SZ_WF + SZ_PXF);
        float*   zbias = Wpx32 + FF * H4;
        float*   zdec0 = zbias + H4;

        hipFuncSetAttribute((const void*)lstm_rec10,
                            hipFuncAttributeMaxDynamicSharedMemorySize, SMEM_TOT);

        prep_consts<<<4, 256, 0, stream>>>(W_pe, b_pe, embed, W_x, b_lstm,
                                           bn_gamma, bn_beta, bn_mean, bn_var,
                                           Wpx32, zbias, zdec0);
        prep_wfrag<<<512, 64, 0, stream>>>(W_x, W_h, whf, wsf);
        prep_wpxf<<<64, 64, 0, stream>>>(Wpx32, wpxf);
        lstm_rec10<<<NWG, 512, SMEM_TOT, stream>>>(whf, wsf, wpxf, pulse,
                                                   zbias, zdec0, b_lstm,
                                                   W_mlp, b_mlp, scale_w, scale_b, out);
        return;
    }

    const size_t NW = (size_t)HH * H4;
    bool use_bf16 = ws_size >= 3 * NW * sizeof(__hip_bfloat16);
    __hip_bfloat16* wxb = (__hip_bfloat16*)d_ws;
    __hip_bfloat16* whb = wxb + NW;
    __hip_bfloat16* wsb = whb + NW;

    if (use_bf16) {
        prep_weights<<<(int)((NW + 255) / 256), 256, 0, stream>>>(W_x, W_h, wxb, whb, wsb);
        lstm_persist<true><<<BB, 512, 0, stream>>>(
            pulse, bn_gamma, bn_beta, bn_mean, bn_var, W_pe, b_pe, embed,
            W_x, W_h, b_lstm, W_mlp, b_mlp, scale_w, scale_b,
            (const void*)wxb, (const void*)whb, (const void*)wsb, out);
    } else {
        lstm_persist<false><<<BB, 512, 0, stream>>>(
            pulse, bn_gamma, bn_beta, bn_mean, bn_var, W_pe, b_pe, embed,
            W_x, W_h, b_lstm, W_mlp, b_mlp, scale_w, scale_b,
            nullptr, nullptr, nullptr, out);
    }
}